// Round 4
// baseline (479.611 us; speedup 1.0000x reference)
//
#include <hip/hip_runtime.h>

// ---------------------------------------------------------------------------
// HopfieldLayer via 3x MX-fp8 MFMA GEMMs (mfma_scale_f32_16x16x128_f8f6f4,
// uniform scales = 1.0). Softmax folded: GEMM2 stores F = 32*(exp(beta*l)-1)
// in fp8 + fp32 row sums; GEMM3 computes
// out = (colsum + F@xi/32) / (8192 + rowsum/32) with exact fp32 colsum.
// fp8 outputs are packed 4B/lane -> K-permuted layout (sigma within
// 128-chunks) matched by xi8/xit8 prep; dot products are perm-invariant.
//
// R8: R4's exact skeleton (128x128, 4 waves, single-buffered A, 2x
// __syncthreads per K-iter -- the best measured structure, 117us/GEMM) with
// ONE mechanism change: B fragments load GLOBAL->REGISTER directly,
// ping-pong double-buffered across K-iters.
//  Rationale (R4..R7 data): throughput ~ resident-block streams; intra-block
//  pipelines never beat cross-block overlap. R4's iter = MFMA 553cy +
//  ds_reads ~600cy + staging drain ~600cy. B was staged through LDS even
//  though its MFMA operand is 32 CONTIGUOUS global bytes (sigma perm is in
//  xi8/xit8 byte order) -- LDS was a pass-through. Direct B:
//   - halves the vmcnt(0)-drained DMA (A only, 16KB/iter),
//   - halves LDS read traffic + bank conflicts,
//   - B(t+1) loads issue at iter start, covered by the MFMA window, gated
//     by no barrier until the iter-end sync.
//  LDS 32KB -> 16KB. Everything else (A swizzle, epilogues, grids) = R4.
// ---------------------------------------------------------------------------

typedef __attribute__((ext_vector_type(8))) int int8v;   // 32 fp8 bytes
typedef __attribute__((ext_vector_type(4))) float f32x4; // MFMA C/D 16x16

#define NDIM 1024
#define NPAT 8192
#define NROW 8192

__device__ __forceinline__ unsigned f8pack4(float a, float b, float c, float d) {
  int w = __builtin_amdgcn_cvt_pk_fp8_f32(a, b, 0, false);
  w = __builtin_amdgcn_cvt_pk_fp8_f32(c, d, w, true);
  return (unsigned)w;
}
__device__ __forceinline__ unsigned char f8b(float v) {
  return (unsigned char)(__builtin_amdgcn_cvt_pk_fp8_f32(v, v, 0, false) & 0xff);
}
// sigma: original col c (0..127) -> packed byte index (epilogue pack order)
__device__ __forceinline__ int sig(int c) {
  return (c & 64) | ((c & 15) << 2) | ((c >> 4) & 3);
}

__device__ __forceinline__ void gload_lds16(const void* g, void* l) {
  __builtin_amdgcn_global_load_lds(
      (const __attribute__((address_space(1))) unsigned char*)g,
      (__attribute__((address_space(3))) unsigned char*)l,
      16, 0, 0);
}

// --------------------------- prep kernels ----------------------------------

__global__ void cast_f8(const float* __restrict__ in,
                        unsigned* __restrict__ out, float scale, int n4) {
  int i = blockIdx.x * blockDim.x + threadIdx.x;
  if (i < n4) {
    float4 v = ((const float4*)in)[i];
    out[i] = f8pack4(v.x * scale, v.y * scale, v.z * scale, v.w * scale);
  }
}

// xi f32 [8192,1024] -> xi8 fp8(32*xi) [8192,1024] (sigma on d within 128),
// xit8 fp8(32*xi) [1024,8192] (sigma on p within 128), colsum[1024] fp32.
__global__ void xi_prep8(const float* __restrict__ xi,
                         unsigned char* __restrict__ xi8,
                         unsigned char* __restrict__ xit8,
                         float* __restrict__ colsum) {
  __shared__ float t[32][33];
  __shared__ float cs[8][32];
  int tx = threadIdx.x, ty = threadIdx.y;
  int d0 = blockIdx.x * 32, p0 = blockIdx.y * 32;
  int d = d0 + tx;
  int di = (d & ~127) + sig(d & 127);
  float psum = 0.f;
#pragma unroll
  for (int j = 0; j < 32; j += 8) {
    float v = xi[(long)(p0 + ty + j) * NDIM + d];
    t[ty + j][tx] = v;
    psum += v;
    xi8[(long)(p0 + ty + j) * NDIM + di] = f8b(32.f * v);
  }
  cs[ty][tx] = psum;
  __syncthreads();
  if (ty == 0) {
    float s = 0.f;
#pragma unroll
    for (int k = 0; k < 8; ++k) s += cs[k][tx];
    atomicAdd(&colsum[d0 + tx], s);
  }
  int p = p0 + tx;
  int pi = (p & ~127) + sig(p & 127);
#pragma unroll
  for (int j = 0; j < 32; j += 8)
    xit8[(long)(d0 + ty + j) * NPAT + pi] = f8b(32.f * t[tx][ty + j]);
}

// --------------------------- fp8 GEMM --------------------------------------
// acc[m,n] = sum_k A[m,k]*B[n,k]; A:[M,K] fp8, B:[N,K] fp8, K mult of 128.
// Block tile 128x128, BK=128B, 256 threads (4 waves 2x2; wave tile 64x64).
// A via LDS: row = 128B = 4 pair-chunks of 32B; pair-chunk p of row r stored
// at pair-slot p^(r&3); lane operand = one aligned 32B int8v load.
// B direct global->reg: lane (quad,ln), frag nt reads 32 contiguous bytes at
// (col0+wn*64+nt*16+ln)*K + kt*128 + quad*32 (sigma order = global order).
// MODE 0: store fp8(acc/32) packed u32   [GEMM1: q]
// MODE 1: F=32*(exp(beta*acc/32)-1); store fp8(F) packed + rowsum atomics
// MODE 2: store f32 (acc/1024 + colsum[col]) / (8192 + rowsum[row]/32)

#define KITER(BF_CUR, BF_NXT, KT)                                           \
  {                                                                         \
    const long ob = (long)((KT) + 1 < nkt ? (KT) + 1 : nkt - 1) << 7;       \
    _Pragma("unroll") for (int nt = 0; nt < 4; ++nt)                        \
        BF_NXT[nt] = *(const int8v*)(pBf[nt] + ob);                         \
    int8v af[4];                                                            \
    _Pragma("unroll") for (int t = 0; t < 4; ++t)                           \
        af[t] = *(const int8v*)(smem + base_a + t * 2048);                  \
    __builtin_amdgcn_s_setprio(1);                                          \
    _Pragma("unroll") for (int mt = 0; mt < 4; ++mt)                        \
      _Pragma("unroll") for (int nt = 0; nt < 4; ++nt)                      \
        acc[mt][nt] = __builtin_amdgcn_mfma_scale_f32_16x16x128_f8f6f4(     \
            af[mt], BF_CUR[nt], acc[mt][nt], 0, 0, 0, 0x7f7f7f7f, 0,        \
            0x7f7f7f7f);                                                    \
    __builtin_amdgcn_s_setprio(0);                                          \
    __syncthreads();                                                        \
    if ((KT) + 1 < nkt) {                                                   \
      _Pragma("unroll") for (int p = 0; p < 4; ++p)                         \
          gload_lds16(gA[p] + (((long)(KT) + 1) << 7), lA[p]);              \
    }                                                                       \
    __syncthreads();                                                        \
  }

template <int MODE>
__launch_bounds__(256, 2)
__global__ void gemm_f8(const unsigned char* __restrict__ A,
                        const unsigned char* __restrict__ B,
                        void* __restrict__ Cv, int N, int K,
                        const float* __restrict__ beta_ptr,
                        const float* __restrict__ rowsum,
                        const float* __restrict__ colsum,
                        float* __restrict__ rowsum_out) {
  __shared__ unsigned char smem[16384];  // A tile only

  const int tid = threadIdx.x;
  const int wave = tid >> 6;
  const int lane = tid & 63;
  const int wm = wave >> 1, wn = wave & 1;
  const int quad = lane >> 4, ln = lane & 15;

  const long row0 = (long)blockIdx.y * 128;
  const long col0 = (long)blockIdx.x * 128;

  // A staging (R4 verbatim): each gload = 8 rows x 128B; lane -> row lane>>3,
  // slot lane&7; slot s of row r holds global 16B chunk (((s>>1)^(r&3))<<1)|(s&1)
  const int r_in = lane >> 3;
  const int csl = lane & 7;
  const int cg = ((((csl >> 1) ^ (r_in & 3)) << 1) | (csl & 1));
  const unsigned char* gA[4];
  unsigned char* lA[4];
#pragma unroll
  for (int p = 0; p < 4; ++p) {
    int grp = wave * 4 + p;
    gA[p] = A + (row0 + grp * 8 + r_in) * (long)K + cg * 16;
    lA[p] = smem + grp * 1024;
  }

  // A fragment addressing (R4 verbatim): pair-slot (quad^(ln&3)).
  const int ps = (quad ^ (ln & 3)) * 32;
  const int base_a = (wm * 64 + ln) * 128 + ps;

  // B fragment base pointers (direct global; 32B contiguous per lane)
  const unsigned char* pBf[4];
#pragma unroll
  for (int nt = 0; nt < 4; ++nt)
    pBf[nt] = B + (col0 + wn * 64 + nt * 16 + ln) * (long)K + quad * 32;

  f32x4 acc[4][4] = {};
  const int nkt = K >> 7;

  // prologue: B(0) -> regs, stage A(0), sync (drains both)
  int8v bf0[4], bf1[4];
#pragma unroll
  for (int nt = 0; nt < 4; ++nt) bf0[nt] = *(const int8v*)(pBf[nt]);
#pragma unroll
  for (int p = 0; p < 4; ++p) gload_lds16(gA[p], lA[p]);
  __syncthreads();

  for (int kt = 0; kt < nkt; kt += 2) {
    KITER(bf0, bf1, kt)
    KITER(bf1, bf0, kt + 1)
  }

  // epilogue. C/D: col = ln (within 16-tile), row = quad*4 + r.
  if (MODE == 0) {
    unsigned* C32 = (unsigned*)Cv;
    const float s = 1.0f / 32.0f;
#pragma unroll
    for (int mt = 0; mt < 4; ++mt)
#pragma unroll
      for (int r = 0; r < 4; ++r) {
        long row = row0 + wm * 64 + mt * 16 + quad * 4 + r;
        unsigned w = f8pack4(acc[mt][0][r] * s, acc[mt][1][r] * s,
                             acc[mt][2][r] * s, acc[mt][3][r] * s);
        C32[row * (N >> 2) + (col0 >> 2) + wn * 16 + ln] = w;
      }
  } else if (MODE == 1) {
    unsigned* C32 = (unsigned*)Cv;
    const float bs = beta_ptr[0] * (1.0f / 32.0f);
#pragma unroll
    for (int mt = 0; mt < 4; ++mt)
#pragma unroll
      for (int r = 0; r < 4; ++r) {
        long row = row0 + wm * 64 + mt * 16 + quad * 4 + r;
        float e0 = (__expf(bs * acc[mt][0][r]) - 1.0f) * 32.f;
        float e1 = (__expf(bs * acc[mt][1][r]) - 1.0f) * 32.f;
        float e2 = (__expf(bs * acc[mt][2][r]) - 1.0f) * 32.f;
        float e3 = (__expf(bs * acc[mt][3][r]) - 1.0f) * 32.f;
        C32[row * (N >> 2) + (col0 >> 2) + wn * 16 + ln] =
            f8pack4(e0, e1, e2, e3);
        float s = e0 + e1 + e2 + e3;
        s += __shfl_xor(s, 1, 64);
        s += __shfl_xor(s, 2, 64);
        s += __shfl_xor(s, 4, 64);
        s += __shfl_xor(s, 8, 64);
        if (ln == 0) atomicAdd(&rowsum_out[row], s);
      }
  } else {
    float* C = (float*)Cv;
#pragma unroll
    for (int mt = 0; mt < 4; ++mt)
#pragma unroll
      for (int r = 0; r < 4; ++r) {
        long row = row0 + wm * 64 + mt * 16 + quad * 4 + r;
        float inv = 1.0f / (8192.0f + rowsum[row] * (1.0f / 32.0f));
#pragma unroll
        for (int nt = 0; nt < 4; ++nt) {
          long col = col0 + wn * 64 + nt * 16 + ln;
          C[row * N + col] =
              (acc[mt][nt][r] * (1.0f / 1024.0f) + colsum[col]) * inv;
        }
      }
  }
}

// --------------------------- launch ----------------------------------------

extern "C" void kernel_launch(void* const* d_in, const int* in_sizes, int n_in,
                              void* d_out, int out_size, void* d_ws,
                              size_t ws_size, hipStream_t stream) {
  const float* x    = (const float*)d_in[0];
  const float* wq   = (const float*)d_in[1];
  const float* xi   = (const float*)d_in[2];
  const float* beta = (const float*)d_in[3];
  float* out = (float*)d_out;

  char* ws = (char*)d_ws;
  const size_t MB = 1024 * 1024;
  unsigned char* x8   = (unsigned char*)(ws);             //  8 MiB
  unsigned char* wq8  = (unsigned char*)(ws + 8 * MB);    //  1 MiB
  unsigned char* q8   = (unsigned char*)(ws + 9 * MB);    //  8 MiB
  unsigned char* xi8  = (unsigned char*)(ws + 17 * MB);   //  8 MiB
  unsigned char* xit8 = (unsigned char*)(ws + 25 * MB);   //  8 MiB
  float*         rs   = (float*)(ws + 33 * MB);           // 32 KiB
  float*         csum = (float*)(ws + 33 * MB + 32768);   //  4 KiB
  unsigned char* E8   = (unsigned char*)(ws + 34 * MB);   // 64 MiB

  hipMemsetAsync(rs, 0, 36864, stream);  // rs + colsum

  cast_f8<<<(NROW * NDIM / 4) / 256, 256, 0, stream>>>(
      x, (unsigned*)x8, 1.0f, NROW * NDIM / 4);
  cast_f8<<<(NDIM * NDIM / 4) / 256, 256, 0, stream>>>(
      wq, (unsigned*)wq8, 32.0f, NDIM * NDIM / 4);
  xi_prep8<<<dim3(NDIM / 32, NPAT / 32), dim3(32, 8), 0, stream>>>(
      xi, xi8, xit8, csum);

  // GEMM1: q = x @ wq^T (acc = 32q), store fp8(q) packed. 512 blocks.
  gemm_f8<0><<<dim3(NDIM / 128, NROW / 128), 256, 0, stream>>>(
      x8, wq8, q8, NDIM, NDIM, nullptr, nullptr, nullptr, nullptr);

  // GEMM2: F = 32*(exp(beta*q.xi)-1), fp8 packed + rowsums. 4096 blocks.
  gemm_f8<1><<<dim3(NPAT / 128, NROW / 128), 256, 0, stream>>>(
      q8, xi8, E8, NPAT, NDIM, beta, nullptr, nullptr, rs);

  // GEMM3: out = (colsum + F@xi/32) / (8192 + rowsum/32). 512 blocks.
  gemm_f8<2><<<dim3(NDIM / 128, NROW / 128), 256, 0, stream>>>(
      E8, xit8, out, NDIM, NPAT, nullptr, rs, csum, nullptr);
}

// Round 5
// 475.984 us; speedup vs baseline: 1.0076x; 1.0076x over previous
//
#include <hip/hip_runtime.h>

// ---------------------------------------------------------------------------
// HopfieldLayer via 3x MX-fp8 MFMA GEMMs (mfma_scale_f32_16x16x128_f8f6f4,
// uniform scales = 1.0). Softmax folded: GEMM2 stores F = 32*(exp(beta*l)-1)
// in fp8 + fp32 row sums; GEMM3 computes
// out = (colsum + F@xi/32) / (8192 + rowsum/32) with exact fp32 colsum.
// fp8 outputs are packed 4B/lane -> K-permuted layout (sigma within
// 128-chunks) matched by xi8/xit8 prep; dot products are perm-invariant.
//
// R9: R4's exact skeleton (128x128, 4 waves, single-buffered 32KB LDS,
// stage -> sync -> compute -> sync; best measured at 117us/GEMM) with ONE
// goal: cross the 128-register occupancy quartile (waves/CU halves at
// vgpr=64/128/256; every prior round sat at 136-236 unified regs -> 8
// waves/CU -> 2 waves/SIMD, and dur tracked 1/waves across R4-R8).
//  - __launch_bounds__(256, 4): regalloc budget 512/4 = 128 unified regs
//    -> 16 waves/CU -> 4 resident blocks (LDS 4x32KB=128 <= 160KB).
//  - Operand liveness 64 -> 48 VGPR: bf loaded in two halves (nt 0,1 then
//    2,3), 8 MFMAs per half; af[4] + bf[2] live at peak.
//  - Staging pointers: 16 pointer-VGPRs -> per-lane 32-bit voffset + wave-
//    uniform base (compiler folds row0/wave/p/kt terms into SGPRs).
//  Everything else (A/B swizzle, sigma, epilogues, grids) = R4 verbatim.
// ---------------------------------------------------------------------------

typedef __attribute__((ext_vector_type(8))) int int8v;   // 32 fp8 bytes
typedef __attribute__((ext_vector_type(4))) float f32x4; // MFMA C/D 16x16

#define NDIM 1024
#define NPAT 8192
#define NROW 8192

__device__ __forceinline__ unsigned f8pack4(float a, float b, float c, float d) {
  int w = __builtin_amdgcn_cvt_pk_fp8_f32(a, b, 0, false);
  w = __builtin_amdgcn_cvt_pk_fp8_f32(c, d, w, true);
  return (unsigned)w;
}
__device__ __forceinline__ unsigned char f8b(float v) {
  return (unsigned char)(__builtin_amdgcn_cvt_pk_fp8_f32(v, v, 0, false) & 0xff);
}
// sigma: original col c (0..127) -> packed byte index (epilogue pack order)
__device__ __forceinline__ int sig(int c) {
  return (c & 64) | ((c & 15) << 2) | ((c >> 4) & 3);
}

__device__ __forceinline__ void gload_lds16(const void* g, void* l) {
  __builtin_amdgcn_global_load_lds(
      (const __attribute__((address_space(1))) unsigned char*)g,
      (__attribute__((address_space(3))) unsigned char*)l,
      16, 0, 0);
}

// --------------------------- prep kernels ----------------------------------

__global__ void cast_f8(const float* __restrict__ in,
                        unsigned* __restrict__ out, float scale, int n4) {
  int i = blockIdx.x * blockDim.x + threadIdx.x;
  if (i < n4) {
    float4 v = ((const float4*)in)[i];
    out[i] = f8pack4(v.x * scale, v.y * scale, v.z * scale, v.w * scale);
  }
}

// xi f32 [8192,1024] -> xi8 fp8(32*xi) [8192,1024] (sigma on d within 128),
// xit8 fp8(32*xi) [1024,8192] (sigma on p within 128), colsum[1024] fp32.
__global__ void xi_prep8(const float* __restrict__ xi,
                         unsigned char* __restrict__ xi8,
                         unsigned char* __restrict__ xit8,
                         float* __restrict__ colsum) {
  __shared__ float t[32][33];
  __shared__ float cs[8][32];
  int tx = threadIdx.x, ty = threadIdx.y;
  int d0 = blockIdx.x * 32, p0 = blockIdx.y * 32;
  int d = d0 + tx;
  int di = (d & ~127) + sig(d & 127);
  float psum = 0.f;
#pragma unroll
  for (int j = 0; j < 32; j += 8) {
    float v = xi[(long)(p0 + ty + j) * NDIM + d];
    t[ty + j][tx] = v;
    psum += v;
    xi8[(long)(p0 + ty + j) * NDIM + di] = f8b(32.f * v);
  }
  cs[ty][tx] = psum;
  __syncthreads();
  if (ty == 0) {
    float s = 0.f;
#pragma unroll
    for (int k = 0; k < 8; ++k) s += cs[k][tx];
    atomicAdd(&colsum[d0 + tx], s);
  }
  int p = p0 + tx;
  int pi = (p & ~127) + sig(p & 127);
#pragma unroll
  for (int j = 0; j < 32; j += 8)
    xit8[(long)(d0 + ty + j) * NPAT + pi] = f8b(32.f * t[tx][ty + j]);
}

// --------------------------- fp8 GEMM --------------------------------------
// acc[m,n] = sum_k A[m,k]*B[n,k]; A:[M,K] fp8, B:[N,K] fp8, K mult of 128.
// Block tile 128x128, BK=128B, 256 threads (4 waves 2x2; wave tile 64x64).
// LDS row = 128B = 4 pair-chunks of 32B; pair-chunk p of row r stored at
// pair-slot p^(r&3). Lane (q,ln) operand = one aligned int8v load.
// MODE 0: store fp8(acc/32) packed u32   [GEMM1: q]
// MODE 1: F=32*(exp(beta*acc/32)-1); store fp8(F) packed + rowsum atomics
// MODE 2: store f32 (acc/1024 + colsum[col]) / (8192 + rowsum[row]/32)

template <int MODE>
__launch_bounds__(256, 4)
__global__ void gemm_f8(const unsigned char* __restrict__ A,
                        const unsigned char* __restrict__ B,
                        void* __restrict__ Cv, int N, int K,
                        const float* __restrict__ beta_ptr,
                        const float* __restrict__ rowsum,
                        const float* __restrict__ colsum,
                        float* __restrict__ rowsum_out) {
  __shared__ unsigned char smem[32768];

  const int tid = threadIdx.x;
  const int wave = tid >> 6;
  const int lane = tid & 63;
  const int wm = wave >> 1, wn = wave & 1;
  const int quad = lane >> 4, ln = lane & 15;

  const long row0 = (long)blockIdx.y * 128;
  const long col0 = (long)blockIdx.x * 128;

  // staging: each gload covers 8 rows x 128B; lane -> row lane>>3, slot lane&7.
  // slot s of row r must hold global 16B chunk (((s>>1)^(r&3))<<1)|(s&1)
  const int r_in = lane >> 3;
  const int csl = lane & 7;
  const int cg = ((((csl >> 1) ^ (r_in & 3)) << 1) | (csl & 1));
  // per-lane 32-bit voffset (uniform parts fold to SGPR in the base ptr)
  const int vAB = r_in * K + cg * 16;
  const unsigned char* Au = A + (row0 + wave * 32) * (long)K;  // wave-uniform
  const unsigned char* Bu = B + (col0 + wave * 32) * (long)K;  // wave-uniform

  // fragment addressing: row R = base+t*16+ln -> R&3 == ln&3, so the
  // swizzled pair-slot (quad ^ (R&3)) is tile-independent.
  const int ps = (quad ^ (ln & 3)) * 32;
  const int base_a = (wm * 64 + ln) * 128 + ps;
  const int base_b = 16384 + (wn * 64 + ln) * 128 + ps;

  f32x4 acc[4][4] = {};
  const int nkt = K >> 7;

  for (int kt = 0; kt < nkt; ++kt) {
    const long kb = (long)kt << 7;
    // stage tile kt (A: rows wave*32+p*8.., B: cols wave*32+p*8..)
#pragma unroll
    for (int p = 0; p < 4; ++p)
      gload_lds16(Au + (vAB + kb + (long)p * 8 * K),
                  smem + (wave * 4 + p) * 1024);
#pragma unroll
    for (int p = 0; p < 4; ++p)
      gload_lds16(Bu + (vAB + kb + (long)p * 8 * K),
                  smem + 16384 + (wave * 4 + p) * 1024);
    __syncthreads();

    // compute: af all 4; bf in two halves to cap live operands at 48 VGPR
    int8v af[4], bf[2];
#pragma unroll
    for (int t = 0; t < 4; ++t)
      af[t] = *(const int8v*)(smem + base_a + t * 2048);
#pragma unroll
    for (int u = 0; u < 2; ++u)
      bf[u] = *(const int8v*)(smem + base_b + u * 2048);
    __builtin_amdgcn_s_setprio(1);
#pragma unroll
    for (int mt = 0; mt < 4; ++mt)
#pragma unroll
      for (int nt = 0; nt < 2; ++nt)
        acc[mt][nt] = __builtin_amdgcn_mfma_scale_f32_16x16x128_f8f6f4(
            af[mt], bf[nt], acc[mt][nt], 0, 0, 0, 0x7f7f7f7f, 0, 0x7f7f7f7f);
    __builtin_amdgcn_s_setprio(0);
#pragma unroll
    for (int u = 0; u < 2; ++u)
      bf[u] = *(const int8v*)(smem + base_b + (2 + u) * 2048);
    __builtin_amdgcn_s_setprio(1);
#pragma unroll
    for (int mt = 0; mt < 4; ++mt)
#pragma unroll
      for (int nt = 0; nt < 2; ++nt)
        acc[mt][2 + nt] = __builtin_amdgcn_mfma_scale_f32_16x16x128_f8f6f4(
            af[mt], bf[nt], acc[mt][2 + nt], 0, 0, 0, 0x7f7f7f7f, 0,
            0x7f7f7f7f);
    __builtin_amdgcn_s_setprio(0);
    __syncthreads();
  }

  // epilogue. C/D: col = ln (within 16-tile), row = quad*4 + r.
  if (MODE == 0) {
    unsigned* C32 = (unsigned*)Cv;
    const float s = 1.0f / 32.0f;
#pragma unroll
    for (int mt = 0; mt < 4; ++mt)
#pragma unroll
      for (int r = 0; r < 4; ++r) {
        long row = row0 + wm * 64 + mt * 16 + quad * 4 + r;
        unsigned w = f8pack4(acc[mt][0][r] * s, acc[mt][1][r] * s,
                             acc[mt][2][r] * s, acc[mt][3][r] * s);
        C32[row * (N >> 2) + (col0 >> 2) + wn * 16 + ln] = w;
      }
  } else if (MODE == 1) {
    unsigned* C32 = (unsigned*)Cv;
    const float bs = beta_ptr[0] * (1.0f / 32.0f);
#pragma unroll
    for (int mt = 0; mt < 4; ++mt)
#pragma unroll
      for (int r = 0; r < 4; ++r) {
        long row = row0 + wm * 64 + mt * 16 + quad * 4 + r;
        float e0 = (__expf(bs * acc[mt][0][r]) - 1.0f) * 32.f;
        float e1 = (__expf(bs * acc[mt][1][r]) - 1.0f) * 32.f;
        float e2 = (__expf(bs * acc[mt][2][r]) - 1.0f) * 32.f;
        float e3 = (__expf(bs * acc[mt][3][r]) - 1.0f) * 32.f;
        C32[row * (N >> 2) + (col0 >> 2) + wn * 16 + ln] =
            f8pack4(e0, e1, e2, e3);
        float s = e0 + e1 + e2 + e3;
        s += __shfl_xor(s, 1, 64);
        s += __shfl_xor(s, 2, 64);
        s += __shfl_xor(s, 4, 64);
        s += __shfl_xor(s, 8, 64);
        if (ln == 0) atomicAdd(&rowsum_out[row], s);
      }
  } else {
    float* C = (float*)Cv;
#pragma unroll
    for (int mt = 0; mt < 4; ++mt)
#pragma unroll
      for (int r = 0; r < 4; ++r) {
        long row = row0 + wm * 64 + mt * 16 + quad * 4 + r;
        float inv = 1.0f / (8192.0f + rowsum[row] * (1.0f / 32.0f));
#pragma unroll
        for (int nt = 0; nt < 4; ++nt) {
          long col = col0 + wn * 64 + nt * 16 + ln;
          C[row * N + col] =
              (acc[mt][nt][r] * (1.0f / 1024.0f) + colsum[col]) * inv;
        }
      }
  }
}

// --------------------------- launch ----------------------------------------

extern "C" void kernel_launch(void* const* d_in, const int* in_sizes, int n_in,
                              void* d_out, int out_size, void* d_ws,
                              size_t ws_size, hipStream_t stream) {
  const float* x    = (const float*)d_in[0];
  const float* wq   = (const float*)d_in[1];
  const float* xi   = (const float*)d_in[2];
  const float* beta = (const float*)d_in[3];
  float* out = (float*)d_out;

  char* ws = (char*)d_ws;
  const size_t MB = 1024 * 1024;
  unsigned char* x8   = (unsigned char*)(ws);             //  8 MiB
  unsigned char* wq8  = (unsigned char*)(ws + 8 * MB);    //  1 MiB
  unsigned char* q8   = (unsigned char*)(ws + 9 * MB);    //  8 MiB
  unsigned char* xi8  = (unsigned char*)(ws + 17 * MB);   //  8 MiB
  unsigned char* xit8 = (unsigned char*)(ws + 25 * MB);   //  8 MiB
  float*         rs   = (float*)(ws + 33 * MB);           // 32 KiB
  float*         csum = (float*)(ws + 33 * MB + 32768);   //  4 KiB
  unsigned char* E8   = (unsigned char*)(ws + 34 * MB);   // 64 MiB

  hipMemsetAsync(rs, 0, 36864, stream);  // rs + colsum

  cast_f8<<<(NROW * NDIM / 4) / 256, 256, 0, stream>>>(
      x, (unsigned*)x8, 1.0f, NROW * NDIM / 4);
  cast_f8<<<(NDIM * NDIM / 4) / 256, 256, 0, stream>>>(
      wq, (unsigned*)wq8, 32.0f, NDIM * NDIM / 4);
  xi_prep8<<<dim3(NDIM / 32, NPAT / 32), dim3(32, 8), 0, stream>>>(
      xi, xi8, xit8, csum);

  // GEMM1: q = x @ wq^T (acc = 32q), store fp8(q) packed. 512 blocks.
  gemm_f8<0><<<dim3(NDIM / 128, NROW / 128), 256, 0, stream>>>(
      x8, wq8, q8, NDIM, NDIM, nullptr, nullptr, nullptr, nullptr);

  // GEMM2: F = 32*(exp(beta*q.xi)-1), fp8 packed + rowsums. 4096 blocks.
  gemm_f8<1><<<dim3(NPAT / 128, NROW / 128), 256, 0, stream>>>(
      q8, xi8, E8, NPAT, NDIM, beta, nullptr, nullptr, rs);

  // GEMM3: out = (colsum + F@xi/32) / (8192 + rowsum/32). 512 blocks.
  gemm_f8<2><<<dim3(NDIM / 128, NROW / 128), 256, 0, stream>>>(
      E8, xit8, out, NDIM, NPAT, nullptr, rs, csum, nullptr);
}

// Round 6
// 342.612 us; speedup vs baseline: 1.3999x; 1.3893x over previous
//
#include <hip/hip_runtime.h>

// ---------------------------------------------------------------------------
// HopfieldLayer via 3x MX-fp8 MFMA GEMMs (mfma_scale_f32_16x16x128_f8f6f4,
// uniform scales = 1.0). Softmax folded: GEMM2 stores F = 32*(exp(beta*l)-1)
// in fp8 + fp32 row sums; GEMM3 computes
// out = (colsum + F@xi/32) / (8192 + rowsum/32) with exact fp32 colsum.
// All K-orders carry the sigma permutation (within 128-chunks) consistently
// on both operands -> dot products are perm-invariant.
//
// R10: B never touches LDS. All B matrices are prep outputs, so they are
// pre-packed into FRAGMENT-NATIVE layout:
//   Bpack[ct][kt][h][lane][16B],  lane = quad*16+ln, h = 16B-half of the
//   lane's 32B operand  ->  each B fragment = two fully-coalesced
//   global_load_dwordx4 (1KB dense per wave instruction).
// (R8's direct-B failed on stride-K uncoalesced loads; this fixes the
//  mechanism while keeping the byte order R8 proved correct.)
// Consequences vs R4 (best measured, 117us/GEMM):
//  - A-only LDS: DMA halves (16KB/iter), ds_read halves, and A double-
//    buffers within the SAME 32KB footprint (no occupancy loss).
//  - ONE __syncthreads per K-iter, at cluster end: the A(t+1) DMA issued at
//    iter top gets the whole MFMA cluster (~550cy) of cover before the
//    drain (R4 drained immediately after issue; R6's version lost occupancy
//    and cover). B(t+1) reg-loads ping-pong, issued per-nt inside the
//    cluster (~300cy cover vs ~200cy L2 latency).
//  - Liveness capped ~156 regs (af in halves, per-nt B issue);
//    __launch_bounds__(256,3). R9 lesson: budget 40+ under natural = spill
//    disaster; here gap is ~10. Falsifier: WRITE_SIZE >> 82MB = spilling.
// ---------------------------------------------------------------------------

typedef __attribute__((ext_vector_type(4))) int int4v;   // 16 fp8 bytes
typedef __attribute__((ext_vector_type(8))) int int8v;   // 32 fp8 bytes
typedef __attribute__((ext_vector_type(4))) float f32x4; // MFMA C/D 16x16

#define NDIM 1024
#define NPAT 8192
#define NROW 8192

__device__ __forceinline__ unsigned f8pack4(float a, float b, float c, float d) {
  int w = __builtin_amdgcn_cvt_pk_fp8_f32(a, b, 0, false);
  w = __builtin_amdgcn_cvt_pk_fp8_f32(c, d, w, true);
  return (unsigned)w;
}
__device__ __forceinline__ unsigned char f8b(float v) {
  return (unsigned char)(__builtin_amdgcn_cvt_pk_fp8_f32(v, v, 0, false) & 0xff);
}
// sigma: original col c (0..127) -> packed byte index (epilogue pack order)
__device__ __forceinline__ int sig(int c) {
  return (c & 64) | ((c & 15) << 2) | ((c >> 4) & 3);
}
// fragment-native pack address: col, stored-k-pos s (0..127), k-tile kt,
// tiles-per-row nkt  ->  byte offset in packed B
__device__ __forceinline__ long bpack_addr(int col, int s, int kt, int nkt) {
  return (((long)(col >> 4) * nkt + kt) * 2 + ((s >> 4) & 1)) * 1024 +
         ((s >> 5) * 16 + (col & 15)) * 16 + (s & 15);
}

__device__ __forceinline__ void gload_lds16(const void* g, void* l) {
  __builtin_amdgcn_global_load_lds(
      (const __attribute__((address_space(1))) unsigned char*)g,
      (__attribute__((address_space(3))) unsigned char*)l,
      16, 0, 0);
}

// --------------------------- prep kernels ----------------------------------

__global__ void cast_f8(const float* __restrict__ in,
                        unsigned* __restrict__ out, float scale, int n4) {
  int i = blockIdx.x * blockDim.x + threadIdx.x;
  if (i < n4) {
    float4 v = ((const float4*)in)[i];
    out[i] = f8pack4(v.x * scale, v.y * scale, v.z * scale, v.w * scale);
  }
}

// wq f32 [1024,1024] (row = out-dim e = col of B, K = d, plain k-order)
// -> fragment-native pack, scale 32.
__global__ void cast_pack_wq(const float* __restrict__ in,
                             unsigned char* __restrict__ out) {
  int i = blockIdx.x * blockDim.x + threadIdx.x;  // 1024*256
  int e = i >> 8, d = (i & 255) * 4;
  float4 v = ((const float4*)in)[i];
  unsigned w = f8pack4(v.x * 32.f, v.y * 32.f, v.z * 32.f, v.w * 32.f);
  *(unsigned*)(out + bpack_addr(e, d & 127, d >> 7, NDIM >> 7)) = w;
}

// xi f32 [8192,1024] -> xi8  = B of GEMM2 (col=p, K=d, sigma on d),
//                       xit8 = B of GEMM3 (col=d, K=p, sigma on p),
// both fragment-native packed; colsum[1024] fp32.
__global__ void xi_prep8(const float* __restrict__ xi,
                         unsigned char* __restrict__ xi8,
                         unsigned char* __restrict__ xit8,
                         float* __restrict__ colsum) {
  __shared__ float t[32][33];
  __shared__ float cs[8][32];
  int tx = threadIdx.x, ty = threadIdx.y;
  int d0 = blockIdx.x * 32, p0 = blockIdx.y * 32;
  int d = d0 + tx;
  const int s2 = sig(d & 127), kt2 = d >> 7;
  float psum = 0.f;
#pragma unroll
  for (int j = 0; j < 32; j += 8) {
    int p = p0 + ty + j;
    float v = xi[(long)p * NDIM + d];
    t[ty + j][tx] = v;
    psum += v;
    xi8[bpack_addr(p, s2, kt2, NDIM >> 7)] = f8b(32.f * v);
  }
  cs[ty][tx] = psum;
  __syncthreads();
  if (ty == 0) {
    float s = 0.f;
#pragma unroll
    for (int k = 0; k < 8; ++k) s += cs[k][tx];
    atomicAdd(&colsum[d0 + tx], s);
  }
  int p = p0 + tx;
  const int s3 = sig(p & 127), kt3 = p >> 7;
#pragma unroll
  for (int j = 0; j < 32; j += 8)
    xit8[bpack_addr(d0 + ty + j, s3, kt3, NPAT >> 7)] = f8b(32.f * t[tx][ty + j]);
}

// --------------------------- fp8 GEMM --------------------------------------
// acc[m,n] = sum_k A[m,k]*B[n,k]; A:[M,K] fp8 row-major, B fragment-packed.
// Block tile 128x128, BK=128B, 256 threads (4 waves 2x2; wave tile 64x64).
// A via LDS (R4 pair-chunk swizzle), double-buffered 2x16KB.
// B direct global->reg, coalesced, ping-pong across K-iters.
// MODE 0: store fp8(acc/32) packed u32   [GEMM1: q]
// MODE 1: F=32*(exp(beta*acc/32)-1); store fp8(F) packed + rowsum atomics
// MODE 2: store f32 (acc/1024 + colsum[col]) / (8192 + rowsum[row]/32)

#define MFMA1(D, AF, BF) \
  D = __builtin_amdgcn_mfma_scale_f32_16x16x128_f8f6f4( \
      AF, BF, D, 0, 0, 0, 0x7f7f7f7f, 0, 0x7f7f7f7f);

#define KBODY(KT, BUF, CUR, NXT)                                            \
  {                                                                         \
    const long o1 = ((long)(((KT) + 1 < nkt) ? (KT) + 1 : (KT))) << 7;      \
    _Pragma("unroll") for (int p = 0; p < 4; ++p)                           \
        gload_lds16(Arow + (vA[p] + o1),                                    \
                    smem + ((BUF) ^ 16384) + (wave * 4 + p) * 1024);        \
    int8v af0 = *(const int8v*)(smem + (BUF) + base_a);                     \
    int8v af1 = *(const int8v*)(smem + (BUF) + base_a + 2048);              \
    __builtin_amdgcn_s_setprio(1);                                          \
    _Pragma("unroll") for (int nt = 0; nt < 4; ++nt) {                      \
      int4v lo = *(const int4v*)(pBf[nt] + 2048);                           \
      int4v hi = *(const int4v*)(pBf[nt] + 3072);                           \
      NXT[nt] = __builtin_shufflevector(lo, hi, 0, 1, 2, 3, 4, 5, 6, 7);    \
      MFMA1(acc[0][nt], af0, CUR[nt])                                       \
      MFMA1(acc[1][nt], af1, CUR[nt])                                       \
    }                                                                       \
    int8v af2 = *(const int8v*)(smem + (BUF) + base_a + 4096);              \
    int8v af3 = *(const int8v*)(smem + (BUF) + base_a + 6144);              \
    _Pragma("unroll") for (int nt = 0; nt < 4; ++nt) {                      \
      MFMA1(acc[2][nt], af2, CUR[nt])                                       \
      MFMA1(acc[3][nt], af3, CUR[nt])                                       \
    }                                                                       \
    __builtin_amdgcn_s_setprio(0);                                          \
    _Pragma("unroll") for (int nt = 0; nt < 4; ++nt) pBf[nt] += 2048;       \
    __syncthreads();                                                        \
  }

template <int MODE>
__launch_bounds__(256, 3)
__global__ void gemm_f8(const unsigned char* __restrict__ A,
                        const unsigned char* __restrict__ Bp,
                        void* __restrict__ Cv, int N, int K,
                        const float* __restrict__ beta_ptr,
                        const float* __restrict__ rowsum,
                        const float* __restrict__ colsum,
                        float* __restrict__ rowsum_out) {
  __shared__ unsigned char smem[32768];  // 2 x 16KB A double buffer

  const int tid = threadIdx.x;
  const int wave = tid >> 6;
  const int lane = tid & 63;
  const int wm = wave >> 1, wn = wave & 1;
  const int quad = lane >> 4, ln = lane & 15;

  const long row0 = (long)blockIdx.y * 128;
  const long col0 = (long)blockIdx.x * 128;
  const int nkt = K >> 7;

  // A staging (R4 verbatim): lane -> row lane>>3, slot lane&7; slot s of
  // row r holds global 16B chunk (((s>>1)^(r&3))<<1)|(s&1)
  const int r_in = lane >> 3;
  const int csl = lane & 7;
  const int cg = ((((csl >> 1) ^ (r_in & 3)) << 1) | (csl & 1));
  const unsigned char* Arow = A + row0 * (long)K;  // block-uniform -> SGPR
  int vA[4];
#pragma unroll
  for (int p = 0; p < 4; ++p) vA[p] = (wave * 32 + p * 8 + r_in) * K + cg * 16;

  // A fragment addressing (R4 verbatim): pair-slot (quad^(ln&3)).
  const int ps = (quad ^ (ln & 3)) * 32;
  const int base_a = (wm * 64 + ln) * 128 + ps;

  // B fragment pointers: frag nt covers col-tile (col0/16 + wn*4 + nt);
  // lane's 32B = two 16B halves at +0 / +1024 within the 2KB (ct,kt) panel.
  const unsigned char* pBf[4];
#pragma unroll
  for (int nt = 0; nt < 4; ++nt)
    pBf[nt] = Bp + ((long)((int)(col0 >> 4) + wn * 4 + nt) * nkt) * 2048 +
              lane * 16;

  f32x4 acc[4][4] = {};
  int8v bC[4], bN[4];

  // prologue: stage A(0)->buf0, load B(0) frags, drain both.
#pragma unroll
  for (int p = 0; p < 4; ++p)
    gload_lds16(Arow + vA[p], smem + (wave * 4 + p) * 1024);
#pragma unroll
  for (int nt = 0; nt < 4; ++nt) {
    int4v lo = *(const int4v*)(pBf[nt]);
    int4v hi = *(const int4v*)(pBf[nt] + 1024);
    bC[nt] = __builtin_shufflevector(lo, hi, 0, 1, 2, 3, 4, 5, 6, 7);
  }
  __syncthreads();

  for (int kt = 0; kt < nkt; kt += 2) {  // nkt is 8 or 64: always even
    KBODY(kt, 0, bC, bN)
    KBODY(kt + 1, 16384, bN, bC)
  }

  // epilogue. C/D: col = ln (within 16-tile), row = quad*4 + r.
  if (MODE == 0) {
    unsigned* C32 = (unsigned*)Cv;
    const float s = 1.0f / 32.0f;
#pragma unroll
    for (int mt = 0; mt < 4; ++mt)
#pragma unroll
      for (int r = 0; r < 4; ++r) {
        long row = row0 + wm * 64 + mt * 16 + quad * 4 + r;
        unsigned w = f8pack4(acc[mt][0][r] * s, acc[mt][1][r] * s,
                             acc[mt][2][r] * s, acc[mt][3][r] * s);
        C32[row * (N >> 2) + (col0 >> 2) + wn * 16 + ln] = w;
      }
  } else if (MODE == 1) {
    unsigned* C32 = (unsigned*)Cv;
    const float bs = beta_ptr[0] * (1.0f / 32.0f);
#pragma unroll
    for (int mt = 0; mt < 4; ++mt)
#pragma unroll
      for (int r = 0; r < 4; ++r) {
        long row = row0 + wm * 64 + mt * 16 + quad * 4 + r;
        float e0 = (__expf(bs * acc[mt][0][r]) - 1.0f) * 32.f;
        float e1 = (__expf(bs * acc[mt][1][r]) - 1.0f) * 32.f;
        float e2 = (__expf(bs * acc[mt][2][r]) - 1.0f) * 32.f;
        float e3 = (__expf(bs * acc[mt][3][r]) - 1.0f) * 32.f;
        C32[row * (N >> 2) + (col0 >> 2) + wn * 16 + ln] =
            f8pack4(e0, e1, e2, e3);
        float s = e0 + e1 + e2 + e3;
        s += __shfl_xor(s, 1, 64);
        s += __shfl_xor(s, 2, 64);
        s += __shfl_xor(s, 4, 64);
        s += __shfl_xor(s, 8, 64);
        if (ln == 0) atomicAdd(&rowsum_out[row], s);
      }
  } else {
    float* C = (float*)Cv;
#pragma unroll
    for (int mt = 0; mt < 4; ++mt)
#pragma unroll
      for (int r = 0; r < 4; ++r) {
        long row = row0 + wm * 64 + mt * 16 + quad * 4 + r;
        float inv = 1.0f / (8192.0f + rowsum[row] * (1.0f / 32.0f));
#pragma unroll
        for (int nt = 0; nt < 4; ++nt) {
          long col = col0 + wn * 64 + nt * 16 + ln;
          C[row * N + col] =
              (acc[mt][nt][r] * (1.0f / 1024.0f) + colsum[col]) * inv;
        }
      }
  }
}

// --------------------------- launch ----------------------------------------

extern "C" void kernel_launch(void* const* d_in, const int* in_sizes, int n_in,
                              void* d_out, int out_size, void* d_ws,
                              size_t ws_size, hipStream_t stream) {
  const float* x    = (const float*)d_in[0];
  const float* wq   = (const float*)d_in[1];
  const float* xi   = (const float*)d_in[2];
  const float* beta = (const float*)d_in[3];
  float* out = (float*)d_out;

  char* ws = (char*)d_ws;
  const size_t MB = 1024 * 1024;
  unsigned char* x8   = (unsigned char*)(ws);             //  8 MiB (plain)
  unsigned char* wq8  = (unsigned char*)(ws + 8 * MB);    //  1 MiB (packed)
  unsigned char* q8   = (unsigned char*)(ws + 9 * MB);    //  8 MiB (rows)
  unsigned char* xi8  = (unsigned char*)(ws + 17 * MB);   //  8 MiB (packed)
  unsigned char* xit8 = (unsigned char*)(ws + 25 * MB);   //  8 MiB (packed)
  float*         rs   = (float*)(ws + 33 * MB);           // 32 KiB
  float*         csum = (float*)(ws + 33 * MB + 32768);   //  4 KiB
  unsigned char* E8   = (unsigned char*)(ws + 34 * MB);   // 64 MiB (rows)

  hipMemsetAsync(rs, 0, 36864, stream);  // rs + colsum

  cast_f8<<<(NROW * NDIM / 4) / 256, 256, 0, stream>>>(
      x, (unsigned*)x8, 1.0f, NROW * NDIM / 4);
  cast_pack_wq<<<(NDIM * NDIM / 4) / 256, 256, 0, stream>>>(wq, wq8);
  xi_prep8<<<dim3(NDIM / 32, NPAT / 32), dim3(32, 8), 0, stream>>>(
      xi, xi8, xit8, csum);

  // GEMM1: q = x @ wq^T (acc = 32q), store fp8(q) packed. 512 blocks.
  gemm_f8<0><<<dim3(NDIM / 128, NROW / 128), 256, 0, stream>>>(
      x8, wq8, q8, NDIM, NDIM, nullptr, nullptr, nullptr, nullptr);

  // GEMM2: F = 32*(exp(beta*q.xi)-1), fp8 packed + rowsums. 4096 blocks.
  gemm_f8<1><<<dim3(NPAT / 128, NROW / 128), 256, 0, stream>>>(
      q8, xi8, E8, NPAT, NDIM, beta, nullptr, nullptr, rs);

  // GEMM3: out = (colsum + F@xi/32) / (8192 + rowsum/32). 512 blocks.
  gemm_f8<2><<<dim3(NDIM / 128, NROW / 128), 256, 0, stream>>>(
      E8, xit8, out, NDIM, NPAT, nullptr, rs, csum, nullptr);
}